// Round 2
// baseline (468.475 us; speedup 1.0000x reference)
//
#include <hip/hip_runtime.h>

// RelationLayer fused implementation, round 2.
// All fp32 (threshold is 8*eps_fp32; no fp32 MFMA on CDNA4 -> VALU GEMMs).
//
// Pipeline (5 kernels, no memset, no atomics):
//  conv  : yT[c][row] (row=l*32+b). win1: 16-row tiles x2 col-halves (K=512).
//          win3: 8-row tiles, K=1536 tap-major, register accumulation.
//          Conv bias skipped: BN subtracts the mean, bias cancels exactly.
//  stats : per-channel mean/var -> scale/shift (folds BN + gamma/beta).
//  ab    : h = leaky(y*scale+shift)*mask on the fly; a = h@w0[:C], bb = h@w0[C:].
//  pair  : per (i,b-pair): p0=leaky(a_i+bb_j+b0) as 128x128 LDS tile (XOR-swizzled
//          -> all LDS traffic <=2-way banked), 3 fused layers (8x8 reg tiles,
//          W-chunk register prefetch across barriers), j-mean -> pmean.
//  out   : pmean -> leaky(@w4+b4) -> leaky(@w5+b5)*mask, 16-row x 256-col tiles.
//
// Swizzle: element (c, r) of the 128x128 tile lives at
//   c*128 + (((r>>2) ^ ((c>>3)&7)) << 2) + (r&3)
// so transposed float4 writes along r land on banks 4*((r>>2)^(tx>>1)) -> 2-way.

#define LL 64
#define BB 32
#define DIN 512
#define CCH 384

__device__ __forceinline__ float leaky(float x) { return x >= 0.f ? x : 0.1f * x; }

// ---------------------------------------------------------------- conv ------
// grid 512: bx 0..255 win3 (8-row tiles), 256..383 win1 h0, 384..511 win1 h1
__global__ __launch_bounds__(256) void conv_kernel(
    const float* __restrict__ x, const float* __restrict__ mask,
    const float* __restrict__ cw0, const float* __restrict__ cw1,
    float* __restrict__ yT)
{
  __shared__ float As[32 * 18];
  __shared__ float Ws[32 * 132];
  int bx = blockIdx.x;
  int tid = threadIdx.x;

  if (bx < 256) {
    // ---- win3: rows row0..row0+7, cols 256..383, K = 3 taps x 512 ----
    int row0 = bx * 8;
    int ct = tid & 31, rt = tid >> 5;      // compute: cols 4*ct, 1 row rt
    int c4 = ct * 4;
    int sk = tid >> 3, sr = tid & 7;       // staging: 1 float each
    int row = row0 + sr;
    int b = row & 31, l = row >> 5;
    float acc[4] = {0.f, 0.f, 0.f, 0.f};
#pragma unroll 1
    for (int k0 = 0; k0 < 1536; k0 += 32) {
      int tap = k0 >> 9;
      int ls = l + tap - 1;
      bool valid = (unsigned)ls < 64u;
      float xv = 0.f;
      if (valid) xv = x[(ls * BB + b) * DIN + (k0 & 511) + sk] * mask[ls * BB + b];
      float4 wv[4];
#pragma unroll
      for (int rep = 0; rep < 4; ++rep) {
        int slot = rep * 256 + tid;
        int c = slot & 127;
        int kq4 = (slot >> 7) * 4;
        wv[rep] = *(const float4*)(cw1 + c * 1536 + k0 + kq4);
      }
      __syncthreads();
      As[sk * 18 + sr] = xv;
#pragma unroll
      for (int rep = 0; rep < 4; ++rep) {
        int slot = rep * 256 + tid;
        int c = slot & 127;
        int kq4 = (slot >> 7) * 4;
        Ws[(kq4 + 0) * 132 + c] = wv[rep].x;
        Ws[(kq4 + 1) * 132 + c] = wv[rep].y;
        Ws[(kq4 + 2) * 132 + c] = wv[rep].z;
        Ws[(kq4 + 3) * 132 + c] = wv[rep].w;
      }
      __syncthreads();
#pragma unroll
      for (int cc = 0; cc < 32; ++cc) {
        float a = As[cc * 18 + rt];
        float4 w = *(const float4*)&Ws[cc * 132 + c4];
        acc[0] = fmaf(a, w.x, acc[0]);
        acc[1] = fmaf(a, w.y, acc[1]);
        acc[2] = fmaf(a, w.z, acc[2]);
        acc[3] = fmaf(a, w.w, acc[3]);
      }
    }
#pragma unroll
    for (int ci = 0; ci < 4; ++ci)
      yT[(256 + c4 + ci) * 2048 + row0 + rt] = acc[ci];
  } else {
    // ---- win1: 16-row tiles, 128-col half h ----
    int h = (bx >> 7) & 1;
    int rt16 = bx & 127;
    int row0 = rt16 * 16;
    int cbase = h * 128;
    const float* wsrc = cw0 + cbase * 512;
    int ct = tid & 31, rr = tid >> 5;      // compute: cols 4ct, rows 2rr..+1
    int c4 = ct * 4, r2 = rr * 2;
    int sr = tid & 15, skh = tid >> 4;     // staging: row sr, k 2skh..+1
    int row = row0 + sr;
    int b = row & 31, l = row >> 5;
    const float* xrow = x + (l * BB + b) * DIN;
    float mval = mask[l * BB + b];
    float acc[2][4] = {{0.f,0.f,0.f,0.f},{0.f,0.f,0.f,0.f}};
#pragma unroll 1
    for (int k0 = 0; k0 < 512; k0 += 32) {
      float2 xv = *(const float2*)(xrow + k0 + 2 * skh);
      float4 wv[4];
#pragma unroll
      for (int rep = 0; rep < 4; ++rep) {
        int slot = rep * 256 + tid;
        int c = slot & 127;
        int kq4 = (slot >> 7) * 4;
        wv[rep] = *(const float4*)(wsrc + c * 512 + k0 + kq4);
      }
      __syncthreads();
      As[(2 * skh + 0) * 18 + sr] = xv.x * mval;
      As[(2 * skh + 1) * 18 + sr] = xv.y * mval;
#pragma unroll
      for (int rep = 0; rep < 4; ++rep) {
        int slot = rep * 256 + tid;
        int c = slot & 127;
        int kq4 = (slot >> 7) * 4;
        Ws[(kq4 + 0) * 132 + c] = wv[rep].x;
        Ws[(kq4 + 1) * 132 + c] = wv[rep].y;
        Ws[(kq4 + 2) * 132 + c] = wv[rep].z;
        Ws[(kq4 + 3) * 132 + c] = wv[rep].w;
      }
      __syncthreads();
#pragma unroll
      for (int cc = 0; cc < 32; ++cc) {
        float2 a = *(const float2*)&As[cc * 18 + r2];
        float4 w = *(const float4*)&Ws[cc * 132 + c4];
        acc[0][0] = fmaf(a.x, w.x, acc[0][0]); acc[0][1] = fmaf(a.x, w.y, acc[0][1]);
        acc[0][2] = fmaf(a.x, w.z, acc[0][2]); acc[0][3] = fmaf(a.x, w.w, acc[0][3]);
        acc[1][0] = fmaf(a.y, w.x, acc[1][0]); acc[1][1] = fmaf(a.y, w.y, acc[1][1]);
        acc[1][2] = fmaf(a.y, w.z, acc[1][2]); acc[1][3] = fmaf(a.y, w.w, acc[1][3]);
      }
    }
#pragma unroll
    for (int ci = 0; ci < 4; ++ci)
      *(float2*)&yT[(cbase + c4 + ci) * 2048 + row0 + r2] =
          make_float2(acc[0][ci], acc[1][ci]);
  }
}

// --------------------------------------------------------------- stats ------
__global__ __launch_bounds__(256) void stats_kernel(
    const float* __restrict__ yT,
    const float* __restrict__ g0, const float* __restrict__ be0,
    const float* __restrict__ g1, const float* __restrict__ be1,
    float* __restrict__ scale, float* __restrict__ shift)
{
  int c = blockIdx.x;
  int tid = threadIdx.x;
  const float* src = yT + c * 2048 + tid * 8;
  float4 v0 = *(const float4*)(src);
  float4 v1 = *(const float4*)(src + 4);
  float s  = v0.x + v0.y + v0.z + v0.w + v1.x + v1.y + v1.z + v1.w;
  float s2 = v0.x*v0.x + v0.y*v0.y + v0.z*v0.z + v0.w*v0.w
           + v1.x*v1.x + v1.y*v1.y + v1.z*v1.z + v1.w*v1.w;
#pragma unroll
  for (int off = 32; off > 0; off >>= 1) {
    s  += __shfl_down(s, off);
    s2 += __shfl_down(s2, off);
  }
  __shared__ float rs[4], rs2[4];
  int wid = tid >> 6;
  if ((tid & 63) == 0) { rs[wid] = s; rs2[wid] = s2; }
  __syncthreads();
  if (tid == 0) {
    float S  = rs[0] + rs[1] + rs[2] + rs[3];
    float S2 = rs2[0] + rs2[1] + rs2[2] + rs2[3];
    float mean = S * (1.f / 2048.f);
    float var  = S2 * (1.f / 2048.f) - mean * mean;
    float g  = (c < 256) ? g0[c] : g1[c - 256];
    float be = (c < 256) ? be0[c] : be1[c - 256];
    float sc = g / sqrtf(var + 1e-5f);
    scale[c] = sc;
    shift[c] = be - mean * sc;
  }
}

// ------------------------------------------------------------------ ab ------
__global__ __launch_bounds__(256) void ab_kernel(
    const float* __restrict__ yT, const float* __restrict__ scale,
    const float* __restrict__ shift, const float* __restrict__ mask,
    const float* __restrict__ w0,
    float* __restrict__ a_arr, float* __restrict__ bb_arr)
{
  __shared__ float As[32 * 36];
  __shared__ float Ws[32 * 68];
  int bx = blockIdx.x;
  int rt = bx & 63, ct = bx >> 6;
  int row0 = rt * 32, n0 = ct * 64;
  int tid = threadIdx.x;
  int r4 = (tid >> 5) * 4;
  int n2 = (tid & 31) * 2;
  int scc = tid >> 3, srr4 = (tid & 7) * 4;
  int wnn8 = (tid & 7) * 8;
  const float* wbase = (n0 < 128) ? (w0 + n0) : (w0 + CCH * 128 + (n0 - 128));
  float4 mv = *(const float4*)(mask + row0 + srr4);

  float acc[4][2] = {{0.f, 0.f}};
#pragma unroll 1
  for (int c0 = 0; c0 < 384; c0 += 32) {
    int c = c0 + scc;
    float4 yv = *(const float4*)(yT + c * 2048 + row0 + srr4);
    float sc = scale[c], sh = shift[c];
    float4 wv0 = *(const float4*)(wbase + c * 128 + wnn8);
    float4 wv1 = *(const float4*)(wbase + c * 128 + wnn8 + 4);
    __syncthreads();
    float4 hv;
    hv.x = leaky(fmaf(yv.x, sc, sh)) * mv.x;
    hv.y = leaky(fmaf(yv.y, sc, sh)) * mv.y;
    hv.z = leaky(fmaf(yv.z, sc, sh)) * mv.z;
    hv.w = leaky(fmaf(yv.w, sc, sh)) * mv.w;
    *(float4*)&As[scc * 36 + srr4] = hv;
    *(float4*)&Ws[scc * 68 + wnn8] = wv0;
    *(float4*)&Ws[scc * 68 + wnn8 + 4] = wv1;
    __syncthreads();
#pragma unroll
    for (int cc = 0; cc < 32; ++cc) {
      float4 a = *(const float4*)&As[cc * 36 + r4];
      float2 w = *(const float2*)&Ws[cc * 68 + n2];
      acc[0][0] = fmaf(a.x, w.x, acc[0][0]); acc[0][1] = fmaf(a.x, w.y, acc[0][1]);
      acc[1][0] = fmaf(a.y, w.x, acc[1][0]); acc[1][1] = fmaf(a.y, w.y, acc[1][1]);
      acc[2][0] = fmaf(a.z, w.x, acc[2][0]); acc[2][1] = fmaf(a.z, w.y, acc[2][1]);
      acc[3][0] = fmaf(a.w, w.x, acc[3][0]); acc[3][1] = fmaf(a.w, w.y, acc[3][1]);
    }
  }
  float* dst; int nd;
  if (n0 < 128) { dst = a_arr; nd = n0; } else { dst = bb_arr; nd = n0 - 128; }
#pragma unroll
  for (int ri = 0; ri < 4; ++ri)
    *(float2*)&dst[(row0 + r4 + ri) * 128 + nd + n2] = make_float2(acc[ri][0], acc[ri][1]);
}

// ---------------------------------------------------------------- pair ------
// grid (64,16), 256 threads, LDS 72KB -> 2 blocks/CU.
__global__ __launch_bounds__(256, 2) void pair_kernel(
    const float* __restrict__ a_arr, const float* __restrict__ bb_arr,
    const float* __restrict__ b0,
    const float* __restrict__ w1, const float* __restrict__ b1,
    const float* __restrict__ w2, const float* __restrict__ b2,
    const float* __restrict__ w3, const float* __restrict__ b3,
    const float* __restrict__ mask, float* __restrict__ pmean)
{
  __shared__ float Al[128 * 128];   // swizzled [c][r] tile
  __shared__ float Wl[16 * 128];    // swizzled W chunk / reduction scratch
  int i = blockIdx.x, bp = blockIdx.y;
  int tid = threadIdx.x;
  int tx = tid & 15, ty = tid >> 4;
  int k0a = 4 * tx;        // thread's k columns: k0a..+3 and k0b..+3
  int k0b = 64 + 4 * tx;
  int r0 = ty * 8;         // thread's 8 rows
  int b  = bp * 2 + (ty >> 3);
  int jbase = r0 & 63;

  // biases for layers 1..3 at this thread's k columns
  float4 bA0 = *(const float4*)(b1 + k0a), bB0 = *(const float4*)(b1 + k0b);
  float4 bA1 = *(const float4*)(b2 + k0a), bB1 = *(const float4*)(b2 + k0b);
  float4 bA2 = *(const float4*)(b3 + k0a), bB2 = *(const float4*)(b3 + k0b);

  // ---- init: p0 = leaky(a_i + bb_j + b0), write transposed+swizzled ----
  {
    const float* arow = a_arr + (i * BB + b) * 128;
    float4 aiA = *(const float4*)(arow + k0a);
    float4 aiB = *(const float4*)(arow + k0b);
    float4 b0A = *(const float4*)(b0 + k0a);
    float4 b0B = *(const float4*)(b0 + k0b);
    float pA[8][4], pB[8][4];
#pragma unroll
    for (int u2 = 0; u2 < 8; ++u2) {
      const float* bbrow = bb_arr + ((jbase + u2) * BB + b) * 128;
      float4 vA = *(const float4*)(bbrow + k0a);
      float4 vB = *(const float4*)(bbrow + k0b);
      pA[u2][0] = leaky(aiA.x + vA.x + b0A.x);
      pA[u2][1] = leaky(aiA.y + vA.y + b0A.y);
      pA[u2][2] = leaky(aiA.z + vA.z + b0A.z);
      pA[u2][3] = leaky(aiA.w + vA.w + b0A.w);
      pB[u2][0] = leaky(aiB.x + vB.x + b0B.x);
      pB[u2][1] = leaky(aiB.y + vB.y + b0B.y);
      pB[u2][2] = leaky(aiB.z + vB.z + b0B.z);
      pB[u2][3] = leaky(aiB.w + vB.w + b0B.w);
    }
#pragma unroll
    for (int u = 0; u < 4; ++u) {
      int k = k0a + u; int s = (k >> 3) & 7;
      float* base = &Al[k * 128];
      *(float4*)&base[((2*ty)^s) << 2]     = make_float4(pA[0][u], pA[1][u], pA[2][u], pA[3][u]);
      *(float4*)&base[((2*ty+1)^s) << 2]   = make_float4(pA[4][u], pA[5][u], pA[6][u], pA[7][u]);
      k = k0b + u; s = (k >> 3) & 7;
      base = &Al[k * 128];
      *(float4*)&base[((2*ty)^s) << 2]     = make_float4(pB[0][u], pB[1][u], pB[2][u], pB[3][u]);
      *(float4*)&base[((2*ty+1)^s) << 2]   = make_float4(pB[4][u], pB[5][u], pB[6][u], pB[7][u]);
    }
  }

  float accA[8][4], accB[8][4];
#pragma unroll
  for (int u = 0; u < 8; ++u)
#pragma unroll
    for (int v = 0; v < 4; ++v) { accA[u][v] = 0.f; accB[u][v] = 0.f; }

  // prefetch W chunk 0 (w1 rows 0..15) into registers
  float4 wnA = *(const float4*)(w1 + ty * 128 + 4 * tx);
  float4 wnB = *(const float4*)(w1 + ty * 128 + 64 + 4 * tx);
  int wsa = ty * 128 + ((tx ^ (ty & 7)) << 2);
  int wsb = ty * 128 + (((16 + tx) ^ (ty & 7)) << 2);

#pragma unroll 1
  for (int layer = 0; layer < 3; ++layer) {
#pragma unroll 1
    for (int ch = 0; ch < 8; ++ch) {
      __syncthreads();                 // prior compute / transpose done
      *(float4*)&Wl[wsa] = wnA;
      *(float4*)&Wl[wsb] = wnB;
      __syncthreads();
      int nc = layer * 8 + ch + 1;
      if (nc < 24) {                   // prefetch next chunk
        const float* Wn = (nc < 8) ? w1 : ((nc < 16) ? w2 : w3);
        const float* src = Wn + ((nc & 7) * 16 + ty) * 128;
        wnA = *(const float4*)(src + 4 * tx);
        wnB = *(const float4*)(src + 64 + 4 * tx);
      }
      int c0 = ch * 16;
#pragma unroll
      for (int cc = 0; cc < 16; ++cc) {
        int c = c0 + cc;
        int s = (c >> 3) & 7;
        const float* abase = &Al[c * 128];
        float4 a0 = *(const float4*)&abase[((2*ty)^s) << 2];
        float4 a1 = *(const float4*)&abase[((2*ty+1)^s) << 2];
        const float* wbase = &Wl[cc * 128];
        float4 wA = *(const float4*)&wbase[((tx ^ (cc & 7))) << 2];
        float4 wB = *(const float4*)&wbase[(((16 + tx) ^ (cc & 7))) << 2];
        float av[8] = {a0.x, a0.y, a0.z, a0.w, a1.x, a1.y, a1.z, a1.w};
        float wa[4] = {wA.x, wA.y, wA.z, wA.w};
        float wb[4] = {wB.x, wB.y, wB.z, wB.w};
#pragma unroll
        for (int u = 0; u < 8; ++u) {
#pragma unroll
          for (int v = 0; v < 4; ++v) {
            accA[u][v] = fmaf(av[u], wa[v], accA[u][v]);
            accB[u][v] = fmaf(av[u], wb[v], accB[u][v]);
          }
        }
      }
    }
    // layer end: bias + leaky
    float4 cbA = (layer == 0) ? bA0 : ((layer == 1) ? bA1 : bA2);
    float4 cbB = (layer == 0) ? bB0 : ((layer == 1) ? bB1 : bB2);
    float baA[4] = {cbA.x, cbA.y, cbA.z, cbA.w};
    float baB[4] = {cbB.x, cbB.y, cbB.z, cbB.w};
#pragma unroll
    for (int u = 0; u < 8; ++u)
#pragma unroll
      for (int v = 0; v < 4; ++v) {
        accA[u][v] = leaky(accA[u][v] + baA[v]);
        accB[u][v] = leaky(accB[u][v] + baB[v]);
      }
    __syncthreads();                   // all Al/Wl reads of this layer done
    if (layer < 2) {
      // transposed swizzled write-back; next iteration's barriers cover visibility
#pragma unroll
      for (int u = 0; u < 4; ++u) {
        int k = k0a + u; int s = (k >> 3) & 7;
        float* base = &Al[k * 128];
        *(float4*)&base[((2*ty)^s) << 2]   = make_float4(accA[0][u], accA[1][u], accA[2][u], accA[3][u]);
        *(float4*)&base[((2*ty+1)^s) << 2] = make_float4(accA[4][u], accA[5][u], accA[6][u], accA[7][u]);
        k = k0b + u; s = (k >> 3) & 7;
        base = &Al[k * 128];
        *(float4*)&base[((2*ty)^s) << 2]   = make_float4(accB[0][u], accB[1][u], accB[2][u], accB[3][u]);
        *(float4*)&base[((2*ty+1)^s) << 2] = make_float4(accB[4][u], accB[5][u], accB[6][u], accB[7][u]);
      }
#pragma unroll
      for (int u = 0; u < 8; ++u)
#pragma unroll
        for (int v = 0; v < 4; ++v) { accA[u][v] = 0.f; accB[u][v] = 0.f; }
    }
  }

  // ---- j-mean: per-thread partials over its 8 rows, reduce via Wl ----
  {
    float pa[4], pb[4];
#pragma unroll
    for (int v = 0; v < 4; ++v) {
      float sa = accA[0][v], sb = accB[0][v];
#pragma unroll
      for (int u = 1; u < 8; ++u) { sa += accA[u][v]; sb += accB[u][v]; }
      pa[v] = sa; pb[v] = sb;
    }
    *(float4*)&Wl[ty * 128 + k0a] = make_float4(pa[0], pa[1], pa[2], pa[3]);
    *(float4*)&Wl[ty * 128 + k0b] = make_float4(pb[0], pb[1], pb[2], pb[3]);
  }
  __syncthreads();
  {
    int db = tid >> 7, k = tid & 127;
    float ssum = 0.f;
#pragma unroll
    for (int t = 0; t < 8; ++t) ssum += Wl[(db * 8 + t) * 128 + k];
    int brow = i * BB + bp * 2 + db;
    pmean[brow * 128 + k] = ssum * (1.0f / 64.0f) * mask[brow];
  }
}

// ----------------------------------------------------------------- out ------
// grid 256 = 128 row-tiles(16) x 2 col-tiles(256)
__global__ __launch_bounds__(256) void out_kernel(
    const float* __restrict__ pmean, const float* __restrict__ w4,
    const float* __restrict__ b4, const float* __restrict__ w5,
    const float* __restrict__ b5, const float* __restrict__ mask,
    float* __restrict__ out)
{
  __shared__ float Pm[16 * 132];
  __shared__ float T4[16 * 132];
  int bx = blockIdx.x;
  int col0 = (bx & 1) * 256;
  int row0 = (bx >> 1) * 16;
  int tid = threadIdx.x;
  int tr = tid >> 4, m = tid & 15;

  {
    const float* src = pmean + (row0 + tr) * 128 + 8 * m;
    *(float4*)&Pm[tr * 132 + 8 * m]     = *(const float4*)(src);
    *(float4*)&Pm[tr * 132 + 8 * m + 4] = *(const float4*)(src + 4);
  }
  __syncthreads();
  {
    int k8 = m * 8;
    float4 bv0 = *(const float4*)(b4 + k8);
    float4 bv1 = *(const float4*)(b4 + k8 + 4);
    float t[8] = {bv0.x, bv0.y, bv0.z, bv0.w, bv1.x, bv1.y, bv1.z, bv1.w};
#pragma unroll 4
    for (int cc = 0; cc < 128; ++cc) {
      float a = Pm[tr * 132 + cc];
      float4 w0v = *(const float4*)(w4 + cc * 128 + k8);
      float4 w1v = *(const float4*)(w4 + cc * 128 + k8 + 4);
      t[0] = fmaf(a, w0v.x, t[0]); t[1] = fmaf(a, w0v.y, t[1]);
      t[2] = fmaf(a, w0v.z, t[2]); t[3] = fmaf(a, w0v.w, t[3]);
      t[4] = fmaf(a, w1v.x, t[4]); t[5] = fmaf(a, w1v.y, t[5]);
      t[6] = fmaf(a, w1v.z, t[6]); t[7] = fmaf(a, w1v.w, t[7]);
    }
    *(float4*)&T4[tr * 132 + k8]     = make_float4(leaky(t[0]), leaky(t[1]), leaky(t[2]), leaky(t[3]));
    *(float4*)&T4[tr * 132 + k8 + 4] = make_float4(leaky(t[4]), leaky(t[5]), leaky(t[6]), leaky(t[7]));
  }
  __syncthreads();
  {
    int c16 = m * 16;
    const float* bsrc = b5 + col0 + c16;
    float o[16];
#pragma unroll
    for (int q = 0; q < 4; ++q) {
      float4 bv = *(const float4*)(bsrc + 4 * q);
      o[4*q+0] = bv.x; o[4*q+1] = bv.y; o[4*q+2] = bv.z; o[4*q+3] = bv.w;
    }
#pragma unroll 2
    for (int cc = 0; cc < 128; ++cc) {
      float a = T4[tr * 132 + cc];
      const float* wr = w5 + cc * 512 + col0 + c16;
#pragma unroll
      for (int q = 0; q < 4; ++q) {
        float4 wv = *(const float4*)(wr + 4 * q);
        o[4*q+0] = fmaf(a, wv.x, o[4*q+0]);
        o[4*q+1] = fmaf(a, wv.y, o[4*q+1]);
        o[4*q+2] = fmaf(a, wv.z, o[4*q+2]);
        o[4*q+3] = fmaf(a, wv.w, o[4*q+3]);
      }
    }
    float mv = mask[row0 + tr];
    float* dst = out + (row0 + tr) * 512 + col0 + c16;
#pragma unroll
    for (int q = 0; q < 4; ++q)
      *(float4*)(dst + 4 * q) = make_float4(leaky(o[4*q+0]) * mv, leaky(o[4*q+1]) * mv,
                                            leaky(o[4*q+2]) * mv, leaky(o[4*q+3]) * mv);
  }
}

// -------------------------------------------------------------- launch ------
extern "C" void kernel_launch(void* const* d_in, const int* in_sizes, int n_in,
                              void* d_out, int out_size, void* d_ws, size_t ws_size,
                              hipStream_t stream) {
  const float* x    = (const float*)d_in[0];
  const float* mask = (const float*)d_in[1];
  const float* cw0  = (const float*)d_in[2];
  // d_in[3] conv_b0: cancels in BN
  const float* g0   = (const float*)d_in[4];
  const float* be0  = (const float*)d_in[5];
  const float* cw1  = (const float*)d_in[6];
  // d_in[7] conv_b1: cancels in BN
  const float* g1   = (const float*)d_in[8];
  const float* be1  = (const float*)d_in[9];
  const float* w0   = (const float*)d_in[10];
  const float* b0   = (const float*)d_in[11];
  const float* w1   = (const float*)d_in[12];
  const float* b1   = (const float*)d_in[13];
  const float* w2   = (const float*)d_in[14];
  const float* b2   = (const float*)d_in[15];
  const float* w3   = (const float*)d_in[16];
  const float* b3   = (const float*)d_in[17];
  const float* w4   = (const float*)d_in[18];
  const float* b4   = (const float*)d_in[19];
  const float* w5   = (const float*)d_in[20];
  const float* b5   = (const float*)d_in[21];

  float* ws     = (float*)d_ws;
  float* yT     = ws;                    // 384*2048
  float* scale  = ws + 786432;           // 384
  float* shift  = ws + 786816;           // 384
  float* a_arr  = ws + 787200;           // 2048*128
  float* bb_arr = ws + 1049344;          // 2048*128
  float* pmean  = ws + 1311488;          // 2048*128
  float* outp   = (float*)d_out;

  conv_kernel<<<512, 256, 0, stream>>>(x, mask, cw0, cw1, yT);
  stats_kernel<<<384, 256, 0, stream>>>(yT, g0, be0, g1, be1, scale, shift);
  ab_kernel<<<256, 256, 0, stream>>>(yT, scale, shift, mask, w0, a_arr, bb_arr);
  dim3 g5(64, 16);
  pair_kernel<<<g5, 256, 0, stream>>>(a_arr, bb_arr, b0, w1, b1, w2, b2, w3, b3,
                                      mask, pmean);
  out_kernel<<<256, 256, 0, stream>>>(pmean, w4, b4, w5, b5, mask, outp);
}

// Round 3
// 401.352 us; speedup vs baseline: 1.1672x; 1.1672x over previous
//
#include <hip/hip_runtime.h>

// RelationLayer, round 3. All fp32 (threshold 8*eps_fp32 forbids bf16 MFMA;
// no fp32 MFMA on CDNA4 -> VALU GEMMs).
//
// Pipeline:
//  conv  : ONE uniform GEMM 2048x640x512: cols 0..255 = win1 conv, cols
//          256+t*128+cc = tap-t partial of win3 (G_t). Recombination
//          y3[row] = G0[row-32] + G1[row] + G2[row+32] happens on the fly in
//          stats/ab (rows = l*32+b, tap shift = +-1 in l = +-32 rows).
//          Conv bias skipped: BN subtracts the mean, bias cancels exactly.
//  stats : per-channel mean/var of (recombined) y -> scale/shift.
//  ab    : h = leaky(y*scale+shift)*mask on the fly; a = h@w0[:C], bb = h@w0[C:].
//  pair  : per (i,b-pair): 128x128 swizzled LDS tile, 3 fused layers, 8x8 reg
//          tiles, j-mean -> pmean. Register-lean: biases loaded per layer,
//          init in two halves (R2's 280MB scratch spill eliminated).
//  out   : pmean -> leaky(@w4+b4) -> leaky(@w5+b5)*mask.

#define BB 32
#define CCH 384

__device__ __forceinline__ float leaky(float x) { return x >= 0.f ? x : 0.1f * x; }

// ---------------------------------------------------------------- conv ------
// grid 320 = 64 row-tiles(32) x 5 col-groups(128). Uniform GEMM blocks.
__global__ __launch_bounds__(256) void conv_kernel(
    const float* __restrict__ x, const float* __restrict__ mask,
    const float* __restrict__ cw0, const float* __restrict__ cw1,
    float* __restrict__ yG)
{
  __shared__ float As[32 * 36];    // [k][r]
  __shared__ float Ws[32 * 132];   // [k][c]
  int bx = blockIdx.x;
  int rt = bx & 63;        // row tile (one l, 32 b's)
  int ct = bx >> 6;        // col group 0..4
  int row0 = rt * 32;
  int tid = threadIdx.x;

  const float* wbase; int wstride;
  if (ct < 2) { wbase = cw0 + ct * 128 * 512; wstride = 512; }
  else        { wbase = cw1 + (ct - 2) * 512; wstride = 1536; }

  // staging: x tile — lanes contiguous along k (coalesced 128B runs)
  int sr  = tid >> 3;            // row 0..31
  int sk4 = (tid & 7) * 4;       // k offset 0..28
  const float* xrow = x + (row0 + sr) * 512;
  float mval = mask[row0 + sr];

  // compute: 4x4 per thread
  int r4 = (tid >> 5) * 4;
  int c4 = (tid & 31) * 4;

  float acc[4][4] = {{0.f,0.f,0.f,0.f},{0.f,0.f,0.f,0.f},
                     {0.f,0.f,0.f,0.f},{0.f,0.f,0.f,0.f}};
#pragma unroll 1
  for (int k0 = 0; k0 < 512; k0 += 32) {
    float4 xv = *(const float4*)(xrow + k0 + sk4);
    float4 wv[4];
#pragma unroll
    for (int rep = 0; rep < 4; ++rep) {
      int slot = rep * 256 + tid;
      int c = slot >> 3;               // 0..127
      int kq4 = (slot & 7) * 4;        // lanes contiguous along k
      wv[rep] = *(const float4*)(wbase + c * wstride + k0 + kq4);
    }
    __syncthreads();
    As[(sk4 + 0) * 36 + sr] = xv.x * mval;
    As[(sk4 + 1) * 36 + sr] = xv.y * mval;
    As[(sk4 + 2) * 36 + sr] = xv.z * mval;
    As[(sk4 + 3) * 36 + sr] = xv.w * mval;
#pragma unroll
    for (int rep = 0; rep < 4; ++rep) {
      int slot = rep * 256 + tid;
      int c = slot >> 3;
      int kq4 = (slot & 7) * 4;
      Ws[(kq4 + 0) * 132 + c] = wv[rep].x;
      Ws[(kq4 + 1) * 132 + c] = wv[rep].y;
      Ws[(kq4 + 2) * 132 + c] = wv[rep].z;
      Ws[(kq4 + 3) * 132 + c] = wv[rep].w;
    }
    __syncthreads();
#pragma unroll
    for (int kk = 0; kk < 32; ++kk) {
      float4 a = *(const float4*)&As[kk * 36 + r4];
      float4 w = *(const float4*)&Ws[kk * 132 + c4];
      float av[4] = {a.x, a.y, a.z, a.w};
      float wv2[4] = {w.x, w.y, w.z, w.w};
#pragma unroll
      for (int ri = 0; ri < 4; ++ri)
#pragma unroll
        for (int ci = 0; ci < 4; ++ci)
          acc[ri][ci] = fmaf(av[ri], wv2[ci], acc[ri][ci]);
    }
  }
#pragma unroll
  for (int ci = 0; ci < 4; ++ci)
    *(float4*)&yG[(ct * 128 + c4 + ci) * 2048 + row0 + r4] =
        make_float4(acc[0][ci], acc[1][ci], acc[2][ci], acc[3][ci]);
}

// --------------------------------------------------------------- stats ------
__global__ __launch_bounds__(256) void stats_kernel(
    const float* __restrict__ yG,
    const float* __restrict__ g0, const float* __restrict__ be0,
    const float* __restrict__ g1, const float* __restrict__ be1,
    float* __restrict__ scale, float* __restrict__ shift)
{
  int c = blockIdx.x;
  int tid = threadIdx.x;
  float s = 0.f, s2 = 0.f;
  if (c < 256) {
    const float* src = yG + c * 2048 + tid * 8;
    float4 v0 = *(const float4*)(src);
    float4 v1 = *(const float4*)(src + 4);
    s  = v0.x + v0.y + v0.z + v0.w + v1.x + v1.y + v1.z + v1.w;
    s2 = v0.x*v0.x + v0.y*v0.y + v0.z*v0.z + v0.w*v0.w
       + v1.x*v1.x + v1.y*v1.y + v1.z*v1.z + v1.w*v1.w;
  } else {
    int cc = c - 256;
    const float* p0 = yG + (256 + cc) * 2048;
    const float* p1 = yG + (384 + cc) * 2048;
    const float* p2 = yG + (512 + cc) * 2048;
#pragma unroll
    for (int j = 0; j < 8; ++j) {
      int e = tid * 8 + j;
      float v = p1[e];
      if (e >= 32)   v += p0[e - 32];
      if (e < 2016)  v += p2[e + 32];
      s += v; s2 += v * v;
    }
  }
#pragma unroll
  for (int off = 32; off > 0; off >>= 1) {
    s  += __shfl_down(s, off);
    s2 += __shfl_down(s2, off);
  }
  __shared__ float rs[4], rs2[4];
  int wid = tid >> 6;
  if ((tid & 63) == 0) { rs[wid] = s; rs2[wid] = s2; }
  __syncthreads();
  if (tid == 0) {
    float S  = rs[0] + rs[1] + rs[2] + rs[3];
    float S2 = rs2[0] + rs2[1] + rs2[2] + rs2[3];
    float mean = S * (1.f / 2048.f);
    float var  = S2 * (1.f / 2048.f) - mean * mean;
    float g  = (c < 256) ? g0[c] : g1[c - 256];
    float be = (c < 256) ? be0[c] : be1[c - 256];
    float sc = g / sqrtf(var + 1e-5f);
    scale[c] = sc;
    shift[c] = be - mean * sc;
  }
}

// ------------------------------------------------------------------ ab ------
// grid 256 = 64 row-tiles(32) x 4 col-tiles(64).
__global__ __launch_bounds__(256) void ab_kernel(
    const float* __restrict__ yG, const float* __restrict__ scale,
    const float* __restrict__ shift, const float* __restrict__ mask,
    const float* __restrict__ w0,
    float* __restrict__ a_arr, float* __restrict__ bb_arr)
{
  __shared__ float As[32 * 36];
  __shared__ float Ws[32 * 68];
  int bx = blockIdx.x;
  int rt = bx & 63, ct = bx >> 6;
  int row0 = rt * 32, n0 = ct * 64;
  int tid = threadIdx.x;
  int r4 = (tid >> 5) * 4;
  int n2 = (tid & 31) * 2;
  int scc = tid >> 3, srr4 = (tid & 7) * 4;
  int wnn8 = (tid & 7) * 8;
  const float* wbase = (n0 < 128) ? (w0 + n0) : (w0 + CCH * 128 + (n0 - 128));
  float4 mv = *(const float4*)(mask + row0 + srr4);

  float acc[4][2] = {{0.f, 0.f}};
#pragma unroll 1
  for (int c0 = 0; c0 < 384; c0 += 32) {
    int c = c0 + scc;
    float4 yv;
    if (c < 256) {
      yv = *(const float4*)(yG + c * 2048 + row0 + srr4);
    } else {
      int cc = c - 256;
      yv = *(const float4*)(yG + (384 + cc) * 2048 + row0 + srr4);
      if (rt > 0) {
        float4 u = *(const float4*)(yG + (256 + cc) * 2048 + row0 + srr4 - 32);
        yv.x += u.x; yv.y += u.y; yv.z += u.z; yv.w += u.w;
      }
      if (rt < 63) {
        float4 u = *(const float4*)(yG + (512 + cc) * 2048 + row0 + srr4 + 32);
        yv.x += u.x; yv.y += u.y; yv.z += u.z; yv.w += u.w;
      }
    }
    float sc = scale[c], sh = shift[c];
    float4 wv0 = *(const float4*)(wbase + c * 128 + wnn8);
    float4 wv1 = *(const float4*)(wbase + c * 128 + wnn8 + 4);
    __syncthreads();
    float4 hv;
    hv.x = leaky(fmaf(yv.x, sc, sh)) * mv.x;
    hv.y = leaky(fmaf(yv.y, sc, sh)) * mv.y;
    hv.z = leaky(fmaf(yv.z, sc, sh)) * mv.z;
    hv.w = leaky(fmaf(yv.w, sc, sh)) * mv.w;
    *(float4*)&As[scc * 36 + srr4] = hv;
    *(float4*)&Ws[scc * 68 + wnn8] = wv0;
    *(float4*)&Ws[scc * 68 + wnn8 + 4] = wv1;
    __syncthreads();
#pragma unroll
    for (int cc = 0; cc < 32; ++cc) {
      float4 a = *(const float4*)&As[cc * 36 + r4];
      float2 w = *(const float2*)&Ws[cc * 68 + n2];
      acc[0][0] = fmaf(a.x, w.x, acc[0][0]); acc[0][1] = fmaf(a.x, w.y, acc[0][1]);
      acc[1][0] = fmaf(a.y, w.x, acc[1][0]); acc[1][1] = fmaf(a.y, w.y, acc[1][1]);
      acc[2][0] = fmaf(a.z, w.x, acc[2][0]); acc[2][1] = fmaf(a.z, w.y, acc[2][1]);
      acc[3][0] = fmaf(a.w, w.x, acc[3][0]); acc[3][1] = fmaf(a.w, w.y, acc[3][1]);
    }
  }
  float* dst; int nd;
  if (n0 < 128) { dst = a_arr; nd = n0; } else { dst = bb_arr; nd = n0 - 128; }
#pragma unroll
  for (int ri = 0; ri < 4; ++ri)
    *(float2*)&dst[(row0 + r4 + ri) * 128 + nd + n2] = make_float2(acc[ri][0], acc[ri][1]);
}

// ---------------------------------------------------------------- pair ------
// grid (64,16), 256 threads, 72KB LDS -> 2 blocks/CU.
// Swizzle: element (c,r) at Al[c*128 + (((r>>2)^((c>>3)&7))<<2) + (r&3)].
__global__ __launch_bounds__(256, 2) void pair_kernel(
    const float* __restrict__ a_arr, const float* __restrict__ bb_arr,
    const float* __restrict__ b0,
    const float* __restrict__ w1, const float* __restrict__ b1,
    const float* __restrict__ w2, const float* __restrict__ b2,
    const float* __restrict__ w3, const float* __restrict__ b3,
    const float* __restrict__ mask, float* __restrict__ pmean)
{
  __shared__ float Al[128 * 128];
  __shared__ float Wl[16 * 128];
  int i = blockIdx.x, bp = blockIdx.y;
  int tid = threadIdx.x;
  int tx = tid & 15, ty = tid >> 4;
  int b  = bp * 2 + (ty >> 3);
  int jb = (ty & 7) * 8;
  int s_ty = ty & 7;

  // ---- init: p0 = leaky(a_i + bb_j + b0), two 64-col halves (low reg peak) ----
#pragma unroll 1
  for (int H = 0; H < 2; ++H) {
    int ks = H * 64 + 4 * tx;
    float4 ai = *(const float4*)(a_arr + (i * BB + b) * 128 + ks);
    float4 bz = *(const float4*)(b0 + ks);
    float col[8][4];
#pragma unroll
    for (int u2 = 0; u2 < 8; ++u2) {
      float4 v = *(const float4*)(bb_arr + ((jb + u2) * BB + b) * 128 + ks);
      col[u2][0] = leaky(ai.x + v.x + bz.x);
      col[u2][1] = leaky(ai.y + v.y + bz.y);
      col[u2][2] = leaky(ai.z + v.z + bz.z);
      col[u2][3] = leaky(ai.w + v.w + bz.w);
    }
#pragma unroll
    for (int u = 0; u < 4; ++u) {
      int k = ks + u;
      int s = (k >> 3) & 7;
      float* base = &Al[k * 128];
      *(float4*)&base[((2*ty)   ^ s) << 2] = make_float4(col[0][u], col[1][u], col[2][u], col[3][u]);
      *(float4*)&base[((2*ty+1) ^ s) << 2] = make_float4(col[4][u], col[5][u], col[6][u], col[7][u]);
    }
  }

  float accA[8][4], accB[8][4];
#pragma unroll
  for (int u = 0; u < 8; ++u)
#pragma unroll
    for (int v = 0; v < 4; ++v) { accA[u][v] = 0.f; accB[u][v] = 0.f; }

  // prefetch W chunk 0 (w1 rows 0..15)
  float4 wn0 = *(const float4*)(w1 + ty * 128 + 4 * tx);
  float4 wn1 = *(const float4*)(w1 + ty * 128 + 64 + 4 * tx);
  int wst = ty * 128 + ((tx ^ s_ty) << 2);   // +64 for the second quad

#pragma unroll 1
  for (int layer = 0; layer < 3; ++layer) {
#pragma unroll 1
    for (int ch = 0; ch < 8; ++ch) {
      __syncthreads();
      *(float4*)&Wl[wst]      = wn0;
      *(float4*)&Wl[wst + 64] = wn1;
      __syncthreads();
      int nc = layer * 8 + ch + 1;
      if (nc < 24) {
        const float* Wn = (nc < 8) ? w1 : ((nc < 16) ? w2 : w3);
        const float* src = Wn + (nc & 7) * 2048 + ty * 128 + 4 * tx;
        wn0 = *(const float4*)(src);
        wn1 = *(const float4*)(src + 64);
      }
      int c0 = ch * 16;
#pragma unroll
      for (int cc = 0; cc < 16; ++cc) {
        int c = c0 + cc;
        int s = (c >> 3) & 7;
        const float* ab_ = &Al[c * 128];
        float4 a0 = *(const float4*)&ab_[((2*ty)   ^ s) << 2];
        float4 a1 = *(const float4*)&ab_[((2*ty+1) ^ s) << 2];
        const float* wb_ = &Wl[cc * 128];
        int wsw = (tx ^ (cc & 7)) << 2;
        float4 w0v = *(const float4*)&wb_[wsw];
        float4 w1v = *(const float4*)&wb_[64 + wsw];
        float av[8] = {a0.x, a0.y, a0.z, a0.w, a1.x, a1.y, a1.z, a1.w};
        float wa[4] = {w0v.x, w0v.y, w0v.z, w0v.w};
        float wb2[4] = {w1v.x, w1v.y, w1v.z, w1v.w};
#pragma unroll
        for (int u = 0; u < 8; ++u) {
#pragma unroll
          for (int v = 0; v < 4; ++v) {
            accA[u][v] = fmaf(av[u], wa[v], accA[u][v]);
            accB[u][v] = fmaf(av[u], wb2[v], accB[u][v]);
          }
        }
      }
    }
    // layer end: bias + leaky (biases loaded HERE, not held across kernel)
    {
      const float* bptr = (layer == 0) ? b1 : ((layer == 1) ? b2 : b3);
      float4 e0 = *(const float4*)(bptr + 4 * tx);
      float4 e1 = *(const float4*)(bptr + 64 + 4 * tx);
      float ea[4] = {e0.x, e0.y, e0.z, e0.w};
      float eb[4] = {e1.x, e1.y, e1.z, e1.w};
#pragma unroll
      for (int u = 0; u < 8; ++u)
#pragma unroll
        for (int v = 0; v < 4; ++v) {
          accA[u][v] = leaky(accA[u][v] + ea[v]);
          accB[u][v] = leaky(accB[u][v] + eb[v]);
        }
    }
    __syncthreads();                 // all Al/Wl reads of this layer done
    if (layer < 2) {
#pragma unroll
      for (int u = 0; u < 4; ++u) {
        int k = 4 * tx + u;
        int s = (k >> 3) & 7;
        float* base = &Al[k * 128];
        *(float4*)&base[((2*ty)   ^ s) << 2] = make_float4(accA[0][u], accA[1][u], accA[2][u], accA[3][u]);
        *(float4*)&base[((2*ty+1) ^ s) << 2] = make_float4(accA[4][u], accA[5][u], accA[6][u], accA[7][u]);
        int k2 = 64 + 4 * tx + u;
        int s2 = (k2 >> 3) & 7;
        base = &Al[k2 * 128];
        *(float4*)&base[((2*ty)   ^ s2) << 2] = make_float4(accB[0][u], accB[1][u], accB[2][u], accB[3][u]);
        *(float4*)&base[((2*ty+1) ^ s2) << 2] = make_float4(accB[4][u], accB[5][u], accB[6][u], accB[7][u]);
      }
#pragma unroll
      for (int u = 0; u < 8; ++u)
#pragma unroll
        for (int v = 0; v < 4; ++v) { accA[u][v] = 0.f; accB[u][v] = 0.f; }
    }
  }

  // ---- j-mean: per-thread partials over 8 rows, reduce via Wl ----
  {
    float pa[4], pb[4];
#pragma unroll
    for (int v = 0; v < 4; ++v) {
      float sa = accA[0][v], sb = accB[0][v];
#pragma unroll
      for (int u = 1; u < 8; ++u) { sa += accA[u][v]; sb += accB[u][v]; }
      pa[v] = sa; pb[v] = sb;
    }
    *(float4*)&Wl[ty * 128 + 4 * tx]      = make_float4(pa[0], pa[1], pa[2], pa[3]);
    *(float4*)&Wl[ty * 128 + 64 + 4 * tx] = make_float4(pb[0], pb[1], pb[2], pb[3]);
  }
  __syncthreads();
  {
    int db = tid >> 7, k = tid & 127;
    float ssum = 0.f;
#pragma unroll
    for (int t = 0; t < 8; ++t) ssum += Wl[(db * 8 + t) * 128 + k];
    int brow = i * BB + bp * 2 + db;
    pmean[brow * 128 + k] = ssum * (1.0f / 64.0f) * mask[brow];
  }
}

// ----------------------------------------------------------------- out ------
// grid 256 = 128 row-tiles(16) x 2 col-tiles(256)
__global__ __launch_bounds__(256) void out_kernel(
    const float* __restrict__ pmean, const float* __restrict__ w4,
    const float* __restrict__ b4, const float* __restrict__ w5,
    const float* __restrict__ b5, const float* __restrict__ mask,
    float* __restrict__ out)
{
  __shared__ float Pm[16 * 132];
  __shared__ float T4[16 * 132];
  int bx = blockIdx.x;
  int col0 = (bx & 1) * 256;
  int row0 = (bx >> 1) * 16;
  int tid = threadIdx.x;
  int tr = tid >> 4, m = tid & 15;

  {
    const float* src = pmean + (row0 + tr) * 128 + 8 * m;
    *(float4*)&Pm[tr * 132 + 8 * m]     = *(const float4*)(src);
    *(float4*)&Pm[tr * 132 + 8 * m + 4] = *(const float4*)(src + 4);
  }
  __syncthreads();
  {
    int k8 = m * 8;
    float4 bv0 = *(const float4*)(b4 + k8);
    float4 bv1 = *(const float4*)(b4 + k8 + 4);
    float t[8] = {bv0.x, bv0.y, bv0.z, bv0.w, bv1.x, bv1.y, bv1.z, bv1.w};
#pragma unroll 4
    for (int cc = 0; cc < 128; ++cc) {
      float a = Pm[tr * 132 + cc];
      float4 w0v = *(const float4*)(w4 + cc * 128 + k8);
      float4 w1v = *(const float4*)(w4 + cc * 128 + k8 + 4);
      t[0] = fmaf(a, w0v.x, t[0]); t[1] = fmaf(a, w0v.y, t[1]);
      t[2] = fmaf(a, w0v.z, t[2]); t[3] = fmaf(a, w0v.w, t[3]);
      t[4] = fmaf(a, w1v.x, t[4]); t[5] = fmaf(a, w1v.y, t[5]);
      t[6] = fmaf(a, w1v.z, t[6]); t[7] = fmaf(a, w1v.w, t[7]);
    }
    *(float4*)&T4[tr * 132 + k8]     = make_float4(leaky(t[0]), leaky(t[1]), leaky(t[2]), leaky(t[3]));
    *(float4*)&T4[tr * 132 + k8 + 4] = make_float4(leaky(t[4]), leaky(t[5]), leaky(t[6]), leaky(t[7]));
  }
  __syncthreads();
  {
    int c16 = m * 16;
    const float* bsrc = b5 + col0 + c16;
    float o[16];
#pragma unroll
    for (int q = 0; q < 4; ++q) {
      float4 bv = *(const float4*)(bsrc + 4 * q);
      o[4*q+0] = bv.x; o[4*q+1] = bv.y; o[4*q+2] = bv.z; o[4*q+3] = bv.w;
    }
#pragma unroll 2
    for (int cc = 0; cc < 128; ++cc) {
      float a = T4[tr * 132 + cc];
      const float* wr = w5 + cc * 512 + col0 + c16;
#pragma unroll
      for (int q = 0; q < 4; ++q) {
        float4 wv = *(const float4*)(wr + 4 * q);
        o[4*q+0] = fmaf(a, wv.x, o[4*q+0]);
        o[4*q+1] = fmaf(a, wv.y, o[4*q+1]);
        o[4*q+2] = fmaf(a, wv.z, o[4*q+2]);
        o[4*q+3] = fmaf(a, wv.w, o[4*q+3]);
      }
    }
    float mv = mask[row0 + tr];
    float* dst = out + (row0 + tr) * 512 + col0 + c16;
#pragma unroll
    for (int q = 0; q < 4; ++q)
      *(float4*)(dst + 4 * q) = make_float4(leaky(o[4*q+0]) * mv, leaky(o[4*q+1]) * mv,
                                            leaky(o[4*q+2]) * mv, leaky(o[4*q+3]) * mv);
  }
}

// -------------------------------------------------------------- launch ------
extern "C" void kernel_launch(void* const* d_in, const int* in_sizes, int n_in,
                              void* d_out, int out_size, void* d_ws, size_t ws_size,
                              hipStream_t stream) {
  const float* x    = (const float*)d_in[0];
  const float* mask = (const float*)d_in[1];
  const float* cw0  = (const float*)d_in[2];
  // d_in[3] conv_b0: cancels in BN
  const float* g0   = (const float*)d_in[4];
  const float* be0  = (const float*)d_in[5];
  const float* cw1  = (const float*)d_in[6];
  // d_in[7] conv_b1: cancels in BN
  const float* g1   = (const float*)d_in[8];
  const float* be1  = (const float*)d_in[9];
  const float* w0   = (const float*)d_in[10];
  const float* b0   = (const float*)d_in[11];
  const float* w1   = (const float*)d_in[12];
  const float* b1   = (const float*)d_in[13];
  const float* w2   = (const float*)d_in[14];
  const float* b2   = (const float*)d_in[15];
  const float* w3   = (const float*)d_in[16];
  const float* b3   = (const float*)d_in[17];
  const float* w4   = (const float*)d_in[18];
  const float* b4   = (const float*)d_in[19];
  const float* w5   = (const float*)d_in[20];
  const float* b5   = (const float*)d_in[21];

  float* ws     = (float*)d_ws;
  float* yG     = ws;                    // 640*2048 = 1,310,720
  float* pmean  = ws;                    // overlays yG (yG dead after ab)
  float* scale  = ws + 1310720;          // 384
  float* shift  = ws + 1311104;          // 384
  float* a_arr  = ws + 1311488;          // 2048*128
  float* bb_arr = ws + 1573632;          // 2048*128
  float* outp   = (float*)d_out;

  conv_kernel<<<320, 256, 0, stream>>>(x, mask, cw0, cw1, yG);
  stats_kernel<<<384, 256, 0, stream>>>(yG, g0, be0, g1, be1, scale, shift);
  ab_kernel<<<256, 256, 0, stream>>>(yG, scale, shift, mask, w0, a_arr, bb_arr);
  dim3 g5(64, 16);
  pair_kernel<<<g5, 256, 0, stream>>>(a_arr, bb_arr, b0, w1, b1, w2, b2, w3, b3,
                                      mask, pmean);
  out_kernel<<<256, 256, 0, stream>>>(pmean, w4, b4, w5, b5, mask, outp);
}

// Round 4
// 397.808 us; speedup vs baseline: 1.1776x; 1.0089x over previous
//
#include <hip/hip_runtime.h>

// RelationLayer, round 4. All fp32 (threshold 8*eps_fp32 forbids bf16 MFMA;
// no fp32 MFMA on CDNA4 -> VALU GEMMs).
//
// R4 change: pair_kernel __launch_bounds__(256,2) -> (256). The (.,2) bound
// empirically pinned the allocator at 128 VGPRs (R1-R3 all show
// VGPR_Count=128) and forced ~65MB of scratch spill (R3 WRITE_SIZE 74.5MB vs
// ~1MB logical). LDS (72KB) already caps occupancy at 2 blocks/CU = 2
// waves/SIMD, which permits 256 VGPRs -> the bound only caused spill.
// Also: leaky via fmaxf (x>=0 ? x : 0.1x == max(x, 0.1x), bit-identical).
//
// Pipeline:
//  conv  : ONE uniform GEMM 2048x640x512: cols 0..255 = win1 conv, cols
//          256+t*128+cc = tap-t partial of win3. Recombination
//          y3[row] = G0[row-32] + G1[row] + G2[row+32] on the fly in stats/ab.
//          Conv bias skipped: BN subtracts the mean, bias cancels exactly.
//  stats : per-channel mean/var of (recombined) y -> scale/shift.
//  ab    : h = leaky(y*scale+shift)*mask on the fly; a = h@w0[:C], bb = h@w0[C:].
//  pair  : per (i,b-pair): 128x128 swizzled LDS tile, 3 fused layers, 8x8 reg
//          tiles, j-mean -> pmean.
//  out   : pmean -> leaky(@w4+b4) -> leaky(@w5+b5)*mask.

#define BB 32
#define CCH 384

__device__ __forceinline__ float leaky(float x) { return fmaxf(x, 0.1f * x); }

// ---------------------------------------------------------------- conv ------
// grid 320 = 64 row-tiles(32) x 5 col-groups(128). Uniform GEMM blocks.
__global__ __launch_bounds__(256) void conv_kernel(
    const float* __restrict__ x, const float* __restrict__ mask,
    const float* __restrict__ cw0, const float* __restrict__ cw1,
    float* __restrict__ yG)
{
  __shared__ float As[32 * 36];    // [k][r]
  __shared__ float Ws[32 * 132];   // [k][c]
  int bx = blockIdx.x;
  int rt = bx & 63;        // row tile (one l, 32 b's)
  int ct = bx >> 6;        // col group 0..4
  int row0 = rt * 32;
  int tid = threadIdx.x;

  const float* wbase; int wstride;
  if (ct < 2) { wbase = cw0 + ct * 128 * 512; wstride = 512; }
  else        { wbase = cw1 + (ct - 2) * 512; wstride = 1536; }

  // staging: x tile — lanes contiguous along k (coalesced 128B runs)
  int sr  = tid >> 3;            // row 0..31
  int sk4 = (tid & 7) * 4;       // k offset 0..28
  const float* xrow = x + (row0 + sr) * 512;
  float mval = mask[row0 + sr];

  // compute: 4x4 per thread
  int r4 = (tid >> 5) * 4;
  int c4 = (tid & 31) * 4;

  float acc[4][4] = {{0.f,0.f,0.f,0.f},{0.f,0.f,0.f,0.f},
                     {0.f,0.f,0.f,0.f},{0.f,0.f,0.f,0.f}};
#pragma unroll 1
  for (int k0 = 0; k0 < 512; k0 += 32) {
    float4 xv = *(const float4*)(xrow + k0 + sk4);
    float4 wv[4];
#pragma unroll
    for (int rep = 0; rep < 4; ++rep) {
      int slot = rep * 256 + tid;
      int c = slot >> 3;               // 0..127
      int kq4 = (slot & 7) * 4;        // lanes contiguous along k
      wv[rep] = *(const float4*)(wbase + c * wstride + k0 + kq4);
    }
    __syncthreads();
    As[(sk4 + 0) * 36 + sr] = xv.x * mval;
    As[(sk4 + 1) * 36 + sr] = xv.y * mval;
    As[(sk4 + 2) * 36 + sr] = xv.z * mval;
    As[(sk4 + 3) * 36 + sr] = xv.w * mval;
#pragma unroll
    for (int rep = 0; rep < 4; ++rep) {
      int slot = rep * 256 + tid;
      int c = slot >> 3;
      int kq4 = (slot & 7) * 4;
      Ws[(kq4 + 0) * 132 + c] = wv[rep].x;
      Ws[(kq4 + 1) * 132 + c] = wv[rep].y;
      Ws[(kq4 + 2) * 132 + c] = wv[rep].z;
      Ws[(kq4 + 3) * 132 + c] = wv[rep].w;
    }
    __syncthreads();
#pragma unroll
    for (int kk = 0; kk < 32; ++kk) {
      float4 a = *(const float4*)&As[kk * 36 + r4];
      float4 w = *(const float4*)&Ws[kk * 132 + c4];
      float av[4] = {a.x, a.y, a.z, a.w};
      float wv2[4] = {w.x, w.y, w.z, w.w};
#pragma unroll
      for (int ri = 0; ri < 4; ++ri)
#pragma unroll
        for (int ci = 0; ci < 4; ++ci)
          acc[ri][ci] = fmaf(av[ri], wv2[ci], acc[ri][ci]);
    }
  }
#pragma unroll
  for (int ci = 0; ci < 4; ++ci)
    *(float4*)&yG[(ct * 128 + c4 + ci) * 2048 + row0 + r4] =
        make_float4(acc[0][ci], acc[1][ci], acc[2][ci], acc[3][ci]);
}

// --------------------------------------------------------------- stats ------
__global__ __launch_bounds__(256) void stats_kernel(
    const float* __restrict__ yG,
    const float* __restrict__ g0, const float* __restrict__ be0,
    const float* __restrict__ g1, const float* __restrict__ be1,
    float* __restrict__ scale, float* __restrict__ shift)
{
  int c = blockIdx.x;
  int tid = threadIdx.x;
  float s = 0.f, s2 = 0.f;
  if (c < 256) {
    const float* src = yG + c * 2048 + tid * 8;
    float4 v0 = *(const float4*)(src);
    float4 v1 = *(const float4*)(src + 4);
    s  = v0.x + v0.y + v0.z + v0.w + v1.x + v1.y + v1.z + v1.w;
    s2 = v0.x*v0.x + v0.y*v0.y + v0.z*v0.z + v0.w*v0.w
       + v1.x*v1.x + v1.y*v1.y + v1.z*v1.z + v1.w*v1.w;
  } else {
    int cc = c - 256;
    const float* p0 = yG + (256 + cc) * 2048;
    const float* p1 = yG + (384 + cc) * 2048;
    const float* p2 = yG + (512 + cc) * 2048;
#pragma unroll
    for (int j = 0; j < 8; ++j) {
      int e = tid * 8 + j;
      float v = p1[e];
      if (e >= 32)   v += p0[e - 32];
      if (e < 2016)  v += p2[e + 32];
      s += v; s2 += v * v;
    }
  }
#pragma unroll
  for (int off = 32; off > 0; off >>= 1) {
    s  += __shfl_down(s, off);
    s2 += __shfl_down(s2, off);
  }
  __shared__ float rs[4], rs2[4];
  int wid = tid >> 6;
  if ((tid & 63) == 0) { rs[wid] = s; rs2[wid] = s2; }
  __syncthreads();
  if (tid == 0) {
    float S  = rs[0] + rs[1] + rs[2] + rs[3];
    float S2 = rs2[0] + rs2[1] + rs2[2] + rs2[3];
    float mean = S * (1.f / 2048.f);
    float var  = S2 * (1.f / 2048.f) - mean * mean;
    float g  = (c < 256) ? g0[c] : g1[c - 256];
    float be = (c < 256) ? be0[c] : be1[c - 256];
    float sc = g / sqrtf(var + 1e-5f);
    scale[c] = sc;
    shift[c] = be - mean * sc;
  }
}

// ------------------------------------------------------------------ ab ------
// grid 256 = 64 row-tiles(32) x 4 col-tiles(64).
__global__ __launch_bounds__(256) void ab_kernel(
    const float* __restrict__ yG, const float* __restrict__ scale,
    const float* __restrict__ shift, const float* __restrict__ mask,
    const float* __restrict__ w0,
    float* __restrict__ a_arr, float* __restrict__ bb_arr)
{
  __shared__ float As[32 * 36];
  __shared__ float Ws[32 * 68];
  int bx = blockIdx.x;
  int rt = bx & 63, ct = bx >> 6;
  int row0 = rt * 32, n0 = ct * 64;
  int tid = threadIdx.x;
  int r4 = (tid >> 5) * 4;
  int n2 = (tid & 31) * 2;
  int scc = tid >> 3, srr4 = (tid & 7) * 4;
  int wnn8 = (tid & 7) * 8;
  const float* wbase = (n0 < 128) ? (w0 + n0) : (w0 + CCH * 128 + (n0 - 128));
  float4 mv = *(const float4*)(mask + row0 + srr4);

  float acc[4][2] = {{0.f, 0.f}};
#pragma unroll 1
  for (int c0 = 0; c0 < 384; c0 += 32) {
    int c = c0 + scc;
    float4 yv;
    if (c < 256) {
      yv = *(const float4*)(yG + c * 2048 + row0 + srr4);
    } else {
      int cc = c - 256;
      yv = *(const float4*)(yG + (384 + cc) * 2048 + row0 + srr4);
      if (rt > 0) {
        float4 u = *(const float4*)(yG + (256 + cc) * 2048 + row0 + srr4 - 32);
        yv.x += u.x; yv.y += u.y; yv.z += u.z; yv.w += u.w;
      }
      if (rt < 63) {
        float4 u = *(const float4*)(yG + (512 + cc) * 2048 + row0 + srr4 + 32);
        yv.x += u.x; yv.y += u.y; yv.z += u.z; yv.w += u.w;
      }
    }
    float sc = scale[c], sh = shift[c];
    float4 wv0 = *(const float4*)(wbase + c * 128 + wnn8);
    float4 wv1 = *(const float4*)(wbase + c * 128 + wnn8 + 4);
    __syncthreads();
    float4 hv;
    hv.x = leaky(fmaf(yv.x, sc, sh)) * mv.x;
    hv.y = leaky(fmaf(yv.y, sc, sh)) * mv.y;
    hv.z = leaky(fmaf(yv.z, sc, sh)) * mv.z;
    hv.w = leaky(fmaf(yv.w, sc, sh)) * mv.w;
    *(float4*)&As[scc * 36 + srr4] = hv;
    *(float4*)&Ws[scc * 68 + wnn8] = wv0;
    *(float4*)&Ws[scc * 68 + wnn8 + 4] = wv1;
    __syncthreads();
#pragma unroll
    for (int cc = 0; cc < 32; ++cc) {
      float4 a = *(const float4*)&As[cc * 36 + r4];
      float2 w = *(const float2*)&Ws[cc * 68 + n2];
      acc[0][0] = fmaf(a.x, w.x, acc[0][0]); acc[0][1] = fmaf(a.x, w.y, acc[0][1]);
      acc[1][0] = fmaf(a.y, w.x, acc[1][0]); acc[1][1] = fmaf(a.y, w.y, acc[1][1]);
      acc[2][0] = fmaf(a.z, w.x, acc[2][0]); acc[2][1] = fmaf(a.z, w.y, acc[2][1]);
      acc[3][0] = fmaf(a.w, w.x, acc[3][0]); acc[3][1] = fmaf(a.w, w.y, acc[3][1]);
    }
  }
  float* dst; int nd;
  if (n0 < 128) { dst = a_arr; nd = n0; } else { dst = bb_arr; nd = n0 - 128; }
#pragma unroll
  for (int ri = 0; ri < 4; ++ri)
    *(float2*)&dst[(row0 + r4 + ri) * 128 + nd + n2] = make_float2(acc[ri][0], acc[ri][1]);
}

// ---------------------------------------------------------------- pair ------
// grid (64,16), 256 threads, 72KB LDS -> 2 blocks/CU (LDS-capped), so allow
// up to 256 VGPRs: NO min-waves bound (R1-R3's (256,2) pinned 128 regs+spill).
// Swizzle: element (c,r) at Al[c*128 + (((r>>2)^((c>>3)&7))<<2) + (r&3)].
__global__ __launch_bounds__(256) void pair_kernel(
    const float* __restrict__ a_arr, const float* __restrict__ bb_arr,
    const float* __restrict__ b0,
    const float* __restrict__ w1, const float* __restrict__ b1,
    const float* __restrict__ w2, const float* __restrict__ b2,
    const float* __restrict__ w3, const float* __restrict__ b3,
    const float* __restrict__ mask, float* __restrict__ pmean)
{
  __shared__ float Al[128 * 128];
  __shared__ float Wl[16 * 128];
  int i = blockIdx.x, bp = blockIdx.y;
  int tid = threadIdx.x;
  int tx = tid & 15, ty = tid >> 4;
  int b  = bp * 2 + (ty >> 3);
  int jb = (ty & 7) * 8;
  int s_ty = ty & 7;

  // ---- init: p0 = leaky(a_i + bb_j + b0), two 64-col halves ----
#pragma unroll 1
  for (int H = 0; H < 2; ++H) {
    int ks = H * 64 + 4 * tx;
    float4 ai = *(const float4*)(a_arr + (i * BB + b) * 128 + ks);
    float4 bz = *(const float4*)(b0 + ks);
    float col[8][4];
#pragma unroll
    for (int u2 = 0; u2 < 8; ++u2) {
      float4 v = *(const float4*)(bb_arr + ((jb + u2) * BB + b) * 128 + ks);
      col[u2][0] = leaky(ai.x + v.x + bz.x);
      col[u2][1] = leaky(ai.y + v.y + bz.y);
      col[u2][2] = leaky(ai.z + v.z + bz.z);
      col[u2][3] = leaky(ai.w + v.w + bz.w);
    }
#pragma unroll
    for (int u = 0; u < 4; ++u) {
      int k = ks + u;
      int s = (k >> 3) & 7;
      float* base = &Al[k * 128];
      *(float4*)&base[((2*ty)   ^ s) << 2] = make_float4(col[0][u], col[1][u], col[2][u], col[3][u]);
      *(float4*)&base[((2*ty+1) ^ s) << 2] = make_float4(col[4][u], col[5][u], col[6][u], col[7][u]);
    }
  }

  float accA[8][4], accB[8][4];
#pragma unroll
  for (int u = 0; u < 8; ++u)
#pragma unroll
    for (int v = 0; v < 4; ++v) { accA[u][v] = 0.f; accB[u][v] = 0.f; }

  // prefetch W chunk 0 (w1 rows 0..15)
  float4 wn0 = *(const float4*)(w1 + ty * 128 + 4 * tx);
  float4 wn1 = *(const float4*)(w1 + ty * 128 + 64 + 4 * tx);
  int wst = ty * 128 + ((tx ^ s_ty) << 2);   // +64 for the second quad

#pragma unroll 1
  for (int layer = 0; layer < 3; ++layer) {
#pragma unroll 1
    for (int ch = 0; ch < 8; ++ch) {
      __syncthreads();
      *(float4*)&Wl[wst]      = wn0;
      *(float4*)&Wl[wst + 64] = wn1;
      __syncthreads();
      int nc = layer * 8 + ch + 1;
      if (nc < 24) {
        const float* Wn = (nc < 8) ? w1 : ((nc < 16) ? w2 : w3);
        const float* src = Wn + (nc & 7) * 2048 + ty * 128 + 4 * tx;
        wn0 = *(const float4*)(src);
        wn1 = *(const float4*)(src + 64);
      }
      int c0 = ch * 16;
#pragma unroll
      for (int cc = 0; cc < 16; ++cc) {
        int c = c0 + cc;
        int s = (c >> 3) & 7;
        const float* ab_ = &Al[c * 128];
        float4 a0 = *(const float4*)&ab_[((2*ty)   ^ s) << 2];
        float4 a1 = *(const float4*)&ab_[((2*ty+1) ^ s) << 2];
        const float* wb_ = &Wl[cc * 128];
        int wsw = (tx ^ (cc & 7)) << 2;
        float4 w0v = *(const float4*)&wb_[wsw];
        float4 w1v = *(const float4*)&wb_[64 + wsw];
        float av[8] = {a0.x, a0.y, a0.z, a0.w, a1.x, a1.y, a1.z, a1.w};
        float wa[4] = {w0v.x, w0v.y, w0v.z, w0v.w};
        float wb2[4] = {w1v.x, w1v.y, w1v.z, w1v.w};
#pragma unroll
        for (int u = 0; u < 8; ++u) {
#pragma unroll
          for (int v = 0; v < 4; ++v) {
            accA[u][v] = fmaf(av[u], wa[v], accA[u][v]);
            accB[u][v] = fmaf(av[u], wb2[v], accB[u][v]);
          }
        }
      }
    }
    // layer end: bias + leaky (biases loaded HERE, not held across kernel)
    {
      const float* bptr = (layer == 0) ? b1 : ((layer == 1) ? b2 : b3);
      float4 e0 = *(const float4*)(bptr + 4 * tx);
      float4 e1 = *(const float4*)(bptr + 64 + 4 * tx);
      float ea[4] = {e0.x, e0.y, e0.z, e0.w};
      float eb[4] = {e1.x, e1.y, e1.z, e1.w};
#pragma unroll
      for (int u = 0; u < 8; ++u)
#pragma unroll
        for (int v = 0; v < 4; ++v) {
          accA[u][v] = leaky(accA[u][v] + ea[v]);
          accB[u][v] = leaky(accB[u][v] + eb[v]);
        }
    }
    __syncthreads();                 // all Al/Wl reads of this layer done
    if (layer < 2) {
#pragma unroll
      for (int u = 0; u < 4; ++u) {
        int k = 4 * tx + u;
        int s = (k >> 3) & 7;
        float* base = &Al[k * 128];
        *(float4*)&base[((2*ty)   ^ s) << 2] = make_float4(accA[0][u], accA[1][u], accA[2][u], accA[3][u]);
        *(float4*)&base[((2*ty+1) ^ s) << 2] = make_float4(accA[4][u], accA[5][u], accA[6][u], accA[7][u]);
        int k2 = 64 + 4 * tx + u;
        int s2 = (k2 >> 3) & 7;
        base = &Al[k2 * 128];
        *(float4*)&base[((2*ty)   ^ s2) << 2] = make_float4(accB[0][u], accB[1][u], accB[2][u], accB[3][u]);
        *(float4*)&base[((2*ty+1) ^ s2) << 2] = make_float4(accB[4][u], accB[5][u], accB[6][u], accB[7][u]);
      }
#pragma unroll
      for (int u = 0; u < 8; ++u)
#pragma unroll
        for (int v = 0; v < 4; ++v) { accA[u][v] = 0.f; accB[u][v] = 0.f; }
    }
  }

  // ---- j-mean: per-thread partials over 8 rows, reduce via Wl ----
  {
    float pa[4], pb[4];
#pragma unroll
    for (int v = 0; v < 4; ++v) {
      float sa = accA[0][v], sb = accB[0][v];
#pragma unroll
      for (int u = 1; u < 8; ++u) { sa += accA[u][v]; sb += accB[u][v]; }
      pa[v] = sa; pb[v] = sb;
    }
    *(float4*)&Wl[ty * 128 + 4 * tx]      = make_float4(pa[0], pa[1], pa[2], pa[3]);
    *(float4*)&Wl[ty * 128 + 64 + 4 * tx] = make_float4(pb[0], pb[1], pb[2], pb[3]);
  }
  __syncthreads();
  {
    int db = tid >> 7, k = tid & 127;
    float ssum = 0.f;
#pragma unroll
    for (int t = 0; t < 8; ++t) ssum += Wl[(db * 8 + t) * 128 + k];
    int brow = i * BB + bp * 2 + db;
    pmean[brow * 128 + k] = ssum * (1.0f / 64.0f) * mask[brow];
  }
}

// ----------------------------------------------------------------- out ------
// grid 256 = 128 row-tiles(16) x 2 col-tiles(256)
__global__ __launch_bounds__(256) void out_kernel(
    const float* __restrict__ pmean, const float* __restrict__ w4,
    const float* __restrict__ b4, const float* __restrict__ w5,
    const float* __restrict__ b5, const float* __restrict__ mask,
    float* __restrict__ out)
{
  __shared__ float Pm[16 * 132];
  __shared__ float T4[16 * 132];
  int bx = blockIdx.x;
  int col0 = (bx & 1) * 256;
  int row0 = (bx >> 1) * 16;
  int tid = threadIdx.x;
  int tr = tid >> 4, m = tid & 15;

  {
    const float* src = pmean + (row0 + tr) * 128 + 8 * m;
    *(float4*)&Pm[tr * 132 + 8 * m]     = *(const float4*)(src);
    *(float4*)&Pm[tr * 132 + 8 * m + 4] = *(const float4*)(src + 4);
  }
  __syncthreads();
  {
    int k8 = m * 8;
    float4 bv0 = *(const float4*)(b4 + k8);
    float4 bv1 = *(const float4*)(b4 + k8 + 4);
    float t[8] = {bv0.x, bv0.y, bv0.z, bv0.w, bv1.x, bv1.y, bv1.z, bv1.w};
#pragma unroll 4
    for (int cc = 0; cc < 128; ++cc) {
      float a = Pm[tr * 132 + cc];
      float4 w0v = *(const float4*)(w4 + cc * 128 + k8);
      float4 w1v = *(const float4*)(w4 + cc * 128 + k8 + 4);
      t[0] = fmaf(a, w0v.x, t[0]); t[1] = fmaf(a, w0v.y, t[1]);
      t[2] = fmaf(a, w0v.z, t[2]); t[3] = fmaf(a, w0v.w, t[3]);
      t[4] = fmaf(a, w1v.x, t[4]); t[5] = fmaf(a, w1v.y, t[5]);
      t[6] = fmaf(a, w1v.z, t[6]); t[7] = fmaf(a, w1v.w, t[7]);
    }
    *(float4*)&T4[tr * 132 + k8]     = make_float4(leaky(t[0]), leaky(t[1]), leaky(t[2]), leaky(t[3]));
    *(float4*)&T4[tr * 132 + k8 + 4] = make_float4(leaky(t[4]), leaky(t[5]), leaky(t[6]), leaky(t[7]));
  }
  __syncthreads();
  {
    int c16 = m * 16;
    const float* bsrc = b5 + col0 + c16;
    float o[16];
#pragma unroll
    for (int q = 0; q < 4; ++q) {
      float4 bv = *(const float4*)(bsrc + 4 * q);
      o[4*q+0] = bv.x; o[4*q+1] = bv.y; o[4*q+2] = bv.z; o[4*q+3] = bv.w;
    }
#pragma unroll 2
    for (int cc = 0; cc < 128; ++cc) {
      float a = T4[tr * 132 + cc];
      const float* wr = w5 + cc * 512 + col0 + c16;
#pragma unroll
      for (int q = 0; q < 4; ++q) {
        float4 wv = *(const float4*)(wr + 4 * q);
        o[4*q+0] = fmaf(a, wv.x, o[4*q+0]);
        o[4*q+1] = fmaf(a, wv.y, o[4*q+1]);
        o[4*q+2] = fmaf(a, wv.z, o[4*q+2]);
        o[4*q+3] = fmaf(a, wv.w, o[4*q+3]);
      }
    }
    float mv = mask[row0 + tr];
    float* dst = out + (row0 + tr) * 512 + col0 + c16;
#pragma unroll
    for (int q = 0; q < 4; ++q)
      *(float4*)(dst + 4 * q) = make_float4(leaky(o[4*q+0]) * mv, leaky(o[4*q+1]) * mv,
                                            leaky(o[4*q+2]) * mv, leaky(o[4*q+3]) * mv);
  }
}

// -------------------------------------------------------------- launch ------
extern "C" void kernel_launch(void* const* d_in, const int* in_sizes, int n_in,
                              void* d_out, int out_size, void* d_ws, size_t ws_size,
                              hipStream_t stream) {
  const float* x    = (const float*)d_in[0];
  const float* mask = (const float*)d_in[1];
  const float* cw0  = (const float*)d_in[2];
  // d_in[3] conv_b0: cancels in BN
  const float* g0   = (const float*)d_in[4];
  const float* be0  = (const float*)d_in[5];
  const float* cw1  = (const float*)d_in[6];
  // d_in[7] conv_b1: cancels in BN
  const float* g1   = (const float*)d_in[8];
  const float* be1  = (const float*)d_in[9];
  const float* w0   = (const float*)d_in[10];
  const float* b0   = (const float*)d_in[11];
  const float* w1   = (const float*)d_in[12];
  const float* b1   = (const float*)d_in[13];
  const float* w2   = (const float*)d_in[14];
  const float* b2   = (const float*)d_in[15];
  const float* w3   = (const float*)d_in[16];
  const float* b3   = (const float*)d_in[17];
  const float* w4   = (const float*)d_in[18];
  const float* b4   = (const float*)d_in[19];
  const float* w5   = (const float*)d_in[20];
  const float* b5   = (const float*)d_in[21];

  float* ws     = (float*)d_ws;
  float* yG     = ws;                    // 640*2048 = 1,310,720
  float* pmean  = ws;                    // overlays yG (yG dead after ab)
  float* scale  = ws + 1310720;          // 384
  float* shift  = ws + 1311104;          // 384
  float* a_arr  = ws + 1311488;          // 2048*128
  float* bb_arr = ws + 1573632;          // 2048*128
  float* outp   = (float*)d_out;

  conv_kernel<<<320, 256, 0, stream>>>(x, mask, cw0, cw1, yG);
  stats_kernel<<<384, 256, 0, stream>>>(yG, g0, be0, g1, be1, scale, shift);
  ab_kernel<<<256, 256, 0, stream>>>(yG, scale, shift, mask, w0, a_arr, bb_arr);
  dim3 g5(64, 16);
  pair_kernel<<<g5, 256, 0, stream>>>(a_arr, bb_arr, b0, w1, b1, w2, b2, w3, b3,
                                      mask, pmean);
  out_kernel<<<256, 256, 0, stream>>>(pmean, w4, b4, w5, b5, mask, outp);
}